// Round 12
// baseline (417.224 us; speedup 1.0000x reference)
//
#include <hip/hip_runtime.h>
#include <math.h>
#include <float.h>

#define NB 8
#define NC 128
#define NN 2048
#define KNN 20
#define EPSV 1e-5f

// ---- workspace layout (float offsets) ----
#define S_OFF      0            // 1024   (colsum S[b][c])          -- zeroed
#define BN0S_OFF   1024         // 256    (bn0 sum/sumsq)           -- zeroed
#define RESST_OFF  1280         // 16384  (8 layers x [sum1024|sumsq1024]) -- zeroed
#define ZERO_CNT   17664
#define NRM_OFF    17664        // 16384  (per-point sumsq, direct store)
#define SQN_OFF    34048        // 16384
#define F1_OFF     50432        // 16384
#define WCAT_OFF   66816        // 32768  (256 x 128)
#define WCOL_OFF   99584        // 256
#define F128_OFF   99840        // 16384 x 128
#define PQ_OFF     2463232      // 16384 x 256  ([P(128)|Q(128)] per point)
#define X_OFF      6657536      // 3 slots x 2097152 (XA, Y1, Y2)
#define SLOT_SZ    2097152
#define IDX_OFF    12948992     // 327680 ints
#define G_OFF      13276672     // 8 x 2048 x 2048 scores (all batches)
#define XB_OFF     46831104     // second x ping-pong buffer
#define WS_FLOATS  48928256     // 195 MB; d_ws is 256 MiB
// min/max planes (used between k6 and k8 only; Y1/Y2 are dead there)
#define MMN_OFF    (X_OFF + SLOT_SZ)
#define MMX_OFF    (X_OFF + 2 * SLOT_SZ)

// ---- K1: fused per-point sumsq + colsum of data/nrm (one data pass) --------
__launch_bounds__(256)
__global__ void k1_fused(const float* __restrict__ data, float* __restrict__ ws) {
    int b = blockIdx.y;
    int n0 = blockIdx.x * 64;
    int tid = threadIdx.x;
    __shared__ float tile[128][65];     // pad 65: colsum reads 2-way banks
    __shared__ float red[4][64];
    __shared__ float Linv[64];
    int g = tid >> 6, nn = tid & 63;
    const float* dp = data + (size_t)b * NC * NN + n0 + nn;
    float sq = 0.f;
    for (int c = g; c < 128; c += 4) {
        float v = dp[(size_t)c * NN];
        tile[c][nn] = v;
        sq = fmaf(v, v, sq);
    }
    red[g][nn] = sq;
    __syncthreads();
    if (tid < 64) {
        float s = red[0][tid] + red[1][tid] + red[2][tid] + red[3][tid];
        ws[NRM_OFF + b * NN + n0 + tid] = s;
        Linv[tid] = 1.f / (sqrtf(s) + 1e-5f);
    }
    __syncthreads();
    if (tid < 128) {
        float s = 0.f;
#pragma unroll 8
        for (int j = 0; j < 64; ++j) s = fmaf(tile[tid][j], Linv[j], s);
        atomicAdd(&ws[S_OFF + b * NC + tid], s);
    }
}

// ---- K2: F128 (transposed data), f1, sqn -----------------------------------
__launch_bounds__(256)
__global__ void k2_feat(const float* __restrict__ data, float* __restrict__ ws) {
    int b = blockIdx.y;
    int n0 = blockIdx.x * 64;
    int tid = threadIdx.x;
    __shared__ float Sb[NC];
    __shared__ float fT[64][129];       // pad 129: 2-way banks on both phases
    __shared__ float redD[4][64];
    if (tid < NC) Sb[tid] = ws[S_OFF + b * NC + tid];
    __syncthreads();
    int nn = tid & 63, cg = tid >> 6;
    float dotp = 0.f;
    const float* dp = data + (size_t)b * NC * NN + n0 + nn;
    for (int c = cg; c < NC; c += 4) {
        float v = dp[(size_t)c * NN];
        fT[nn][c] = v;
        dotp = fmaf(Sb[c], v, dotp);
    }
    redD[cg][nn] = dotp;
    __syncthreads();
    if (tid < 64) {
        float dt = redD[0][tid] + redD[1][tid] + redD[2][tid] + redD[3][tid];
        float nrmsq = ws[NRM_OFF + b * NN + n0 + tid];
        float nrm = sqrtf(nrmsq) + 1e-5f;
        float D = (dt / nrm - 1.f) * (1.f / (float)NN);
        float f1 = tanhf(D); if (f1 < 0.f) f1 = 0.f;
        ws[F1_OFF + b * NN + n0 + tid] = f1;
        ws[SQN_OFF + b * NN + n0 + tid] = nrmsq + f1 * f1;
    }
    __syncthreads();
    float* out = ws + F128_OFF + (size_t)(b * NN + n0) * 128;
    for (int i = tid; i < 64 * 128; i += 256) out[i] = fT[i >> 7][i & 127];
}

// ---- K4: Wcat128[256][128] = [W1+W2 ; W2] cols 0..127; wcol = column 128 ---
__launch_bounds__(256)
__global__ void k4_wcat(const float* __restrict__ w, float* __restrict__ ws) {
    int i = blockIdx.x * 256 + threadIdx.x;
    if (i < 32768) {
        int o = i >> 7, c = i & 127;
        float v = (o < 128) ? w[o * 258 + c] + w[o * 258 + 129 + c]
                            : w[(o - 128) * 258 + 129 + c];
        ws[WCAT_OFF + i] = v;
    } else if (i < 33024) {
        int o = i - 32768;
        float v = (o < 128) ? w[o * 258 + 128] + w[o * 258 + 257]
                            : w[(o - 128) * 258 + 257];
        ws[WCOL_OFF + o] = v;
    }
}

// ------- K3: G[b][n][m] = 2*(X_n.X_m + f1_n*f1_m) - sq[m], K=128 ------------
// Symmetric triangular pairs split into n-quarters: 32(n) x 128(m) per block,
// acc[2][8], grid 544x8. Off-diagonal blocks also write the transposed stripe.
__launch_bounds__(256)
__global__ void k3_gram(float* __restrict__ ws) {
    __shared__ __align__(16) float As[8][32];
    __shared__ __align__(16) float Bs[8][128];
    int tid = threadIdx.x;
    int b = blockIdx.z;
    int p = blockIdx.x >> 2, quarter = blockIdx.x & 3;
    int a = 0, rem = 16;
    while (p >= rem) { p -= rem; ++a; --rem; }
    int bq = a + p;                      // a <= bq
    int n0 = a * 128 + quarter * 32, m0 = bq * 128;
    const float* F = ws + F128_OFF + (size_t)b * NN * 128;
    float acc[2][8];
#pragma unroll
    for (int i = 0; i < 2; ++i)
#pragma unroll
        for (int j = 0; j < 8; ++j) acc[i][j] = 0.f;
    int rr = tid >> 1, cq = tid & 1;          // B staging: 128 rows x 2 k-halves
    int ar = (tid & 63) >> 1, acq = tid & 1;  // A staging (tid<64): 32 rows
    int tx = tid & 15, ty = tid >> 4;
    for (int kc = 0; kc < 128; kc += 8) {
        float4 bv = *(const float4*)&F[(size_t)(m0 + rr) * 128 + kc + cq * 4];
        float4 av;
        if (tid < 64) av = *(const float4*)&F[(size_t)(n0 + ar) * 128 + kc + acq * 4];
        __syncthreads();
        Bs[cq*4+0][rr] = bv.x; Bs[cq*4+1][rr] = bv.y; Bs[cq*4+2][rr] = bv.z; Bs[cq*4+3][rr] = bv.w;
        if (tid < 64) {
            As[acq*4+0][ar] = av.x; As[acq*4+1][ar] = av.y;
            As[acq*4+2][ar] = av.z; As[acq*4+3][ar] = av.w;
        }
        __syncthreads();
#pragma unroll
        for (int kk = 0; kk < 8; ++kk) {
            float a0 = As[kk][ty * 2], a1 = As[kk][ty * 2 + 1];
            float bb[8];
            *(float4*)&bb[0] = *(const float4*)&Bs[kk][tx * 4];
            *(float4*)&bb[4] = *(const float4*)&Bs[kk][64 + tx * 4];
#pragma unroll
            for (int j = 0; j < 8; ++j) {
                acc[0][j] = fmaf(a0, bb[j], acc[0][j]);
                acc[1][j] = fmaf(a1, bb[j], acc[1][j]);
            }
        }
    }
    const float* F1 = ws + F1_OFF + b * NN;
    const float* SQ = ws + SQN_OFF + b * NN;
    float sqv[8], f1m[8], sqn[2], f1nv[2];
#pragma unroll
    for (int j = 0; j < 4; ++j) {
        sqv[j]     = SQ[m0 + tx * 4 + j];
        sqv[4 + j] = SQ[m0 + 64 + tx * 4 + j];
        f1m[j]     = F1[m0 + tx * 4 + j];
        f1m[4 + j] = F1[m0 + 64 + tx * 4 + j];
    }
#pragma unroll
    for (int i = 0; i < 2; ++i) {
        int n = n0 + ty * 2 + i;
        sqn[i]  = SQ[n];
        f1nv[i] = F1[n];
    }
    float* G = ws + G_OFF + (size_t)b * NN * NN;
    // normal write: rows n-range (32), cols m-range (128), minus sq[m]
#pragma unroll
    for (int i = 0; i < 2; ++i) {
        int row = n0 + ty * 2 + i;
        float f1n = f1nv[i];
        float4 o1, o2;
        o1.x = 2.f*fmaf(f1n, f1m[0], acc[i][0]) - sqv[0];
        o1.y = 2.f*fmaf(f1n, f1m[1], acc[i][1]) - sqv[1];
        o1.z = 2.f*fmaf(f1n, f1m[2], acc[i][2]) - sqv[2];
        o1.w = 2.f*fmaf(f1n, f1m[3], acc[i][3]) - sqv[3];
        o2.x = 2.f*fmaf(f1n, f1m[4], acc[i][4]) - sqv[4];
        o2.y = 2.f*fmaf(f1n, f1m[5], acc[i][5]) - sqv[5];
        o2.z = 2.f*fmaf(f1n, f1m[6], acc[i][6]) - sqv[6];
        o2.w = 2.f*fmaf(f1n, f1m[7], acc[i][7]) - sqv[7];
        *(float4*)&G[(size_t)row * NN + m0 + tx * 4]      = o1;
        *(float4*)&G[(size_t)row * NN + m0 + 64 + tx * 4] = o2;
    }
    if (a != bq) {
        // transposed write: rows m-range (128), cols n-range (32), minus sq[n]
#pragma unroll
        for (int j = 0; j < 8; ++j) {
            int cl = (j < 4) ? (tx * 4 + j) : (64 + tx * 4 + (j - 4));
            size_t grow = (size_t)(m0 + cl) * NN + n0 + ty * 2;
            float f1mj = f1m[j];
            float2 t0;
            t0.x = 2.f*fmaf(f1nv[0], f1mj, acc[0][j]) - sqn[0];
            t0.y = 2.f*fmaf(f1nv[1], f1mj, acc[1][j]) - sqn[1];
            *(float2*)&G[grow] = t0;
        }
    }
}

// ------- KSEL: per-row top-21 (drop first = self) -> idx[20], all batches ---
// Coalesced float4 loads: slot s of lane l = column (s>>2)*256 + l*4 + (s&3).
// Within-lane ascending slot = ascending column; exact top_k tie semantics.
__launch_bounds__(256)
__global__ void ksel(float* __restrict__ ws) {
    int wid = threadIdx.x >> 6, lane = threadIdx.x & 63;
    int r = blockIdx.x * 4 + wid;            // global row 0..16383 (= b*2048+n)
    const float* row = ws + G_OFF + (size_t)r * NN;
    float v[32];
#pragma unroll
    for (int i = 0; i < 8; ++i)
        *(float4*)&v[i * 4] = *(const float4*)&row[i * 256 + lane * 4];
    float b1v = -FLT_MAX, b2v = -FLT_MAX;
    int b1i = 0, b2i = 0;
#pragma unroll
    for (int i = 0; i < 32; ++i) {
        float x = v[i];
        if (x > b1v)      { b2v = b1v; b2i = b1i; b1v = x; b1i = i; }
        else if (x > b2v) { b2v = x; b2i = i; }
    }
    unsigned int mask = 0u;
    bool has2 = true;
    int* out = (int*)(ws + IDX_OFF) + (size_t)r * KNN;
    for (int k = 0; k < 21; ++k) {
        float M = b1v;
#pragma unroll
        for (int off = 1; off < 64; off <<= 1) M = fmaxf(M, __shfl_xor(M, off));
        unsigned long long tied = __ballot(b1v == M);
        int mm;
        if (__popcll(tied) > 1) {
            int cand = (b1v == M) ? ((b1i >> 2) * 256 + lane * 4 + (b1i & 3)) : 0x7FFFFFFF;
#pragma unroll
            for (int off = 1; off < 64; off <<= 1) {
                int oc = __shfl_xor(cand, off);
                cand = oc < cand ? oc : cand;
            }
            mm = cand;
        } else {
            int l = __ffsll(tied) - 1;
            int s = __shfl(b1i, l);
            mm = (s >> 2) * 256 + l * 4 + (s & 3);
        }
        if (k > 0 && lane == 0) out[k - 1] = mm;
        // winner lane: (mm - (mm>>8)*256) / 4 ... recover via column decomposition
        if (lane == ((mm & 255) >> 2)) {
            // could be this lane; verify slot matches our b1i-derived column
            int s_mine = b1i;
            int col_mine = (s_mine >> 2) * 256 + lane * 4 + (s_mine & 3);
            if (col_mine == mm) {
                mask |= 1u << b1i;
                if (has2) { b1v = b2v; b1i = b2i; has2 = false; }
                else {
                    b1v = -FLT_MAX; b2v = -FLT_MAX; b1i = 0; b2i = 0;
#pragma unroll
                    for (int i = 0; i < 32; ++i) {
                        float x = (mask & (1u << i)) ? -FLT_MAX : v[i];
                        if (x > b1v)      { b2v = b1v; b2i = b1i; b1v = x; b1i = i; }
                        else if (x > b2v) { b2v = x; b2i = i; }
                    }
                    has2 = true;
                }
            }
        }
    }
}

// ---- K5: PQ[m][256] = F128[m][128] x Wcat128^T + f1[m]*wcol ---------------
__launch_bounds__(256)
__global__ void k5_pq(float* __restrict__ ws) {
    __shared__ __align__(16) float As[16][64];
    __shared__ __align__(16) float Bs[16][64];
    int tid = threadIdx.x;
    int m0 = blockIdx.x * 64, o0 = blockIdx.y * 64;
    int rr = tid >> 2, cq = tid & 3;
    int tx = tid & 15, ty = tid >> 4;
    float acc[4][4];
#pragma unroll
    for (int i = 0; i < 4; ++i)
#pragma unroll
        for (int j = 0; j < 4; ++j) acc[i][j] = 0.f;
    const float* F  = ws + F128_OFF;
    const float* Wc = ws + WCAT_OFF;
    for (int kc = 0; kc < 128; kc += 16) {
        float4 av = *(const float4*)&F [(size_t)(m0 + rr) * 128 + kc + cq * 4];
        float4 bv = *(const float4*)&Wc[(size_t)(o0 + rr) * 128 + kc + cq * 4];
        __syncthreads();
        As[cq*4+0][rr]=av.x; As[cq*4+1][rr]=av.y; As[cq*4+2][rr]=av.z; As[cq*4+3][rr]=av.w;
        Bs[cq*4+0][rr]=bv.x; Bs[cq*4+1][rr]=bv.y; Bs[cq*4+2][rr]=bv.z; Bs[cq*4+3][rr]=bv.w;
        __syncthreads();
#pragma unroll
        for (int kk = 0; kk < 16; ++kk) {
            float a[4], bb[4];
            *(float4*)&a[0]  = *(const float4*)&As[kk][ty * 4];
            *(float4*)&bb[0] = *(const float4*)&Bs[kk][tx * 4];
#pragma unroll
            for (int i = 0; i < 4; ++i)
#pragma unroll
                for (int j = 0; j < 4; ++j) acc[i][j] = fmaf(a[i], bb[j], acc[i][j]);
        }
    }
    float wc[4], f1v[4];
#pragma unroll
    for (int j = 0; j < 4; ++j) {
        wc[j]  = ws[WCOL_OFF + o0 + tx * 4 + j];
        f1v[j] = ws[F1_OFF + m0 + ty * 4 + j];
    }
#pragma unroll
    for (int i = 0; i < 4; ++i) {
        float4 o;
        o.x = fmaf(f1v[i], wc[0], acc[i][0]);
        o.y = fmaf(f1v[i], wc[1], acc[i][1]);
        o.z = fmaf(f1v[i], wc[2], acc[i][2]);
        o.w = fmaf(f1v[i], wc[3], acc[i][3]);
        *(float4*)&ws[PQ_OFF + (size_t)(m0 + ty * 4 + i) * 256 + o0 + tx * 4] = o;
    }
}

// -------- K6: bn0 stats + per-(m,o) min/max of (P - Q[j]) over neighbors ----
__launch_bounds__(256)
__global__ void k6_bn0stats(float* __restrict__ ws) {
    int tid = threadIdx.x;
    int o = tid & 127, h = tid >> 7;
    int m0 = blockIdx.x * 16;
    const float* PQ = ws + PQ_OFF;
    const int* idx = (const int*)(ws + IDX_OFF);
    float* MMn = ws + MMN_OFF;
    float* MMx = ws + MMX_OFF;
    __shared__ float red[2][128];
    float s = 0.f, q = 0.f;
    for (int p = h; p < 16; p += 2) {
        int m = m0 + p;
        int bb = m >> 11;
        float pv = PQ[(size_t)m * 256 + o];
        const int* ip = idx + (size_t)m * KNN;
        float mn = FLT_MAX, mx = -FLT_MAX;
        for (int k = 0; k < KNN; ++k) {
            int j = ip[k];
            float val = pv - PQ[(size_t)(bb * NN + j) * 256 + 128 + o];
            s += val; q += val * val;
            mn = fminf(mn, val); mx = fmaxf(mx, val);
        }
        MMn[(size_t)m * NC + o] = mn;
        MMx[(size_t)m * NC + o] = mx;
    }
    red[h][o] = s; __syncthreads();
    if (tid < 128) atomicAdd(&ws[BN0S_OFF + tid], red[0][tid] + red[1][tid]);
    __syncthreads();
    red[h][o] = q; __syncthreads();
    if (tid < 128) atomicAdd(&ws[BN0S_OFF + 128 + tid], red[0][tid] + red[1][tid]);
}

// ---- K8: X0 = relu(sc * (sc>0 ? max : min) + sh); affine derived inline ----
__launch_bounds__(256)
__global__ void k8_apply(float* __restrict__ ws, const float* __restrict__ g,
                         const float* __restrict__ be) {
    int e = blockIdx.x * 256 + threadIdx.x;
    int fi = e * 4;
    int o = fi & 127;
    const float cnt = 1.f / (float)(NB * NN * KNN);
    float4 sum4 = *(const float4*)&ws[BN0S_OFF + o];
    float4 ssq4 = *(const float4*)&ws[BN0S_OFF + 128 + o];
    float4 g4   = *(const float4*)&g[o];
    float4 be4  = *(const float4*)&be[o];
    float4 mn = *(const float4*)&ws[MMN_OFF + fi];
    float4 mx = *(const float4*)&ws[MMX_OFF + fi];
    float4 r;
#define BN0_DO(comp) { \
    float m_ = sum4.comp * cnt; \
    float v_ = ssq4.comp * cnt - m_ * m_; if (v_ < 0.f) v_ = 0.f; \
    float sc_ = g4.comp * rsqrtf(v_ + EPSV); \
    float sh_ = be4.comp - m_ * sc_; \
    r.comp = fmaxf(fmaf(sc_ > 0.f ? mx.comp : mn.comp, sc_, sh_), 0.f); }
    BN0_DO(x) BN0_DO(y) BN0_DO(z) BN0_DO(w)
#undef BN0_DO
    *(float4*)&ws[X_OFF + fi] = r;
}

// ---- K9f: res conv GEMM (32m x 64o tiles) + fused per-(b,o) stats.
// If statsIn: derive per-(block-batch) inorm+bn affine from raw stats;
// input t = relu(x*sc + sh [+ xin]). If xw && blockIdx.y==0: write t back.
__launch_bounds__(256)
__global__ void k9f_conv(const float* __restrict__ x, const float* __restrict__ w,
                         float* __restrict__ y, float* __restrict__ stats,
                         const float* __restrict__ statsIn,
                         const float* __restrict__ g, const float* __restrict__ be,
                         const float* __restrict__ xin, float* __restrict__ xw) {
    __shared__ __align__(16) float As[16][32];
    __shared__ __align__(16) float Bs[16][64];
    __shared__ float red[16][64];
    __shared__ float vvv[8][128];
    __shared__ float scs[128], shs[128];
    int tid = threadIdx.x;
    int m0 = blockIdx.x * 32, o0 = blockIdx.y * 64;
    int bA = m0 >> 11;                       // whole block is one batch (32 | 2048)
    if (statsIn) {
        for (int e = tid; e < 1024; e += 256) {
            float sum = statsIn[e], ssq = statsIn[1024 + e];
            float m_ = sum * (1.f / (float)NN);
            float v_ = ssq * (1.f / (float)NN) - m_ * m_; if (v_ < 0.f) v_ = 0.f;
            vvv[e >> 7][e & 127] = v_ / (v_ + EPSV);
        }
        __syncthreads();
        if (tid < 128) {
            float a = 0.f;
#pragma unroll
            for (int b2 = 0; b2 < NB; ++b2) a += vvv[b2][tid];
            float rsbn = rsqrtf(a * (1.f / (float)NB) + EPSV);
            float sum = statsIn[bA * 128 + tid], ssq = statsIn[1024 + bA * 128 + tid];
            float m_ = sum * (1.f / (float)NN);
            float v_ = ssq * (1.f / (float)NN) - m_ * m_; if (v_ < 0.f) v_ = 0.f;
            float sc_ = rsqrtf(v_ + EPSV) * rsbn * g[tid];
            scs[tid] = sc_;
            shs[tid] = be[tid] - m_ * sc_;
        }
        __syncthreads();
    }
    int rr = tid >> 2, cq = tid & 3;              // B staging: 64 rows x 4 chunks
    int ar = (tid & 127) >> 2, acq = tid & 3;     // A staging (tid<128): 32 rows
    int tx = tid & 15, ty = tid >> 4;
    float acc[2][4];
#pragma unroll
    for (int i = 0; i < 2; ++i)
#pragma unroll
        for (int j = 0; j < 4; ++j) acc[i][j] = 0.f;
    for (int kc = 0; kc < NC; kc += 16) {
        float4 av;
        if (tid < 128) {
            av = *(const float4*)&x[(size_t)(m0 + ar) * NC + kc + acq * 4];
            if (statsIn) {
                int c = kc + acq * 4;
                av.x = fmaf(av.x, scs[c],     shs[c]);
                av.y = fmaf(av.y, scs[c + 1], shs[c + 1]);
                av.z = fmaf(av.z, scs[c + 2], shs[c + 2]);
                av.w = fmaf(av.w, scs[c + 3], shs[c + 3]);
                if (xin) {
                    float4 xv = *(const float4*)&xin[(size_t)(m0 + ar) * NC + kc + acq * 4];
                    av.x += xv.x; av.y += xv.y; av.z += xv.z; av.w += xv.w;
                }
                av.x = fmaxf(av.x, 0.f); av.y = fmaxf(av.y, 0.f);
                av.z = fmaxf(av.z, 0.f); av.w = fmaxf(av.w, 0.f);
                if (xw && blockIdx.y == 0)
                    *(float4*)&xw[(size_t)(m0 + ar) * NC + kc + acq * 4] = av;
            }
        }
        float4 bv = *(const float4*)&w[(size_t)(o0 + rr) * NC + kc + cq * 4];
        __syncthreads();
        if (tid < 128) {
            As[acq*4+0][ar]=av.x; As[acq*4+1][ar]=av.y;
            As[acq*4+2][ar]=av.z; As[acq*4+3][ar]=av.w;
        }
        Bs[cq*4+0][rr]=bv.x; Bs[cq*4+1][rr]=bv.y; Bs[cq*4+2][rr]=bv.z; Bs[cq*4+3][rr]=bv.w;
        __syncthreads();
#pragma unroll
        for (int kk = 0; kk < 16; ++kk) {
            float a0 = As[kk][ty * 2], a1 = As[kk][ty * 2 + 1];
            float bb[4];
            *(float4*)&bb[0] = *(const float4*)&Bs[kk][tx * 4];
#pragma unroll
            for (int j = 0; j < 4; ++j) {
                acc[0][j] = fmaf(a0, bb[j], acc[0][j]);
                acc[1][j] = fmaf(a1, bb[j], acc[1][j]);
            }
        }
    }
#pragma unroll
    for (int i = 0; i < 2; ++i) {
        float4 o;
        o.x = acc[i][0]; o.y = acc[i][1]; o.z = acc[i][2]; o.w = acc[i][3];
        *(float4*)&y[(size_t)(m0 + ty * 2 + i) * NC + o0 + tx * 4] = o;
    }
    float s[4], q[4];
#pragma unroll
    for (int j = 0; j < 4; ++j) {
        s[j] = acc[0][j] + acc[1][j];
        q[j] = acc[0][j]*acc[0][j] + acc[1][j]*acc[1][j];
    }
    *(float4*)&red[ty][tx * 4] = make_float4(s[0], s[1], s[2], s[3]);
    __syncthreads();
    if (tid < 64) {
        float t = 0.f;
#pragma unroll
        for (int g2 = 0; g2 < 16; ++g2) t += red[g2][tid];
        atomicAdd(&stats[bA * NC + o0 + tid], t);
    }
    __syncthreads();
    *(float4*)&red[ty][tx * 4] = make_float4(q[0], q[1], q[2], q[3]);
    __syncthreads();
    if (tid < 64) {
        float t = 0.f;
#pragma unroll
        for (int g2 = 0; g2 < 16; ++g2) t += red[g2][tid];
        atomicAdd(&stats[1024 + bA * NC + o0 + tid], t);
    }
}

// ---- K12: logit = lin_w . relu(aff7(y2) + xin) + lin_b; aff derived inline -
__launch_bounds__(256)
__global__ void k12_logit(const float* __restrict__ y2, const float* __restrict__ xin,
                          const float* __restrict__ statsIn,
                          const float* __restrict__ g, const float* __restrict__ be,
                          const float* __restrict__ lw, const float* __restrict__ lb,
                          float* __restrict__ out) {
    __shared__ float wsh[128];
    __shared__ float vvv[8][128];
    __shared__ float scs[128], shs[128];
    int tid = threadIdx.x;
    int b = (blockIdx.x * 256) >> 11;        // whole block one batch (256 | 2048)
    if (tid < 128) wsh[tid] = lw[tid];
    for (int e = tid; e < 1024; e += 256) {
        float sum = statsIn[e], ssq = statsIn[1024 + e];
        float m_ = sum * (1.f / (float)NN);
        float v_ = ssq * (1.f / (float)NN) - m_ * m_; if (v_ < 0.f) v_ = 0.f;
        vvv[e >> 7][e & 127] = v_ / (v_ + EPSV);
    }
    __syncthreads();
    if (tid < 128) {
        float a = 0.f;
#pragma unroll
        for (int b2 = 0; b2 < NB; ++b2) a += vvv[b2][tid];
        float rsbn = rsqrtf(a * (1.f / (float)NB) + EPSV);
        float sum = statsIn[b * 128 + tid], ssq = statsIn[1024 + b * 128 + tid];
        float m_ = sum * (1.f / (float)NN);
        float v_ = ssq * (1.f / (float)NN) - m_ * m_; if (v_ < 0.f) v_ = 0.f;
        float sc_ = rsqrtf(v_ + EPSV) * rsbn * g[tid];
        scs[tid] = sc_;
        shs[tid] = be[tid] - m_ * sc_;
    }
    __syncthreads();
    int m = blockIdx.x * 256 + tid;
    const float* yp = y2 + (size_t)m * NC;
    const float* xp = xin + (size_t)m * NC;
    float acc = lb[0];
    for (int c = 0; c < NC; c += 4) {
        float4 yv = *(const float4*)&yp[c];
        float4 xv = *(const float4*)&xp[c];
        float v0 = fmaxf(fmaf(yv.x, scs[c],     shs[c])     + xv.x, 0.f);
        float v1 = fmaxf(fmaf(yv.y, scs[c + 1], shs[c + 1]) + xv.y, 0.f);
        float v2 = fmaxf(fmaf(yv.z, scs[c + 2], shs[c + 2]) + xv.z, 0.f);
        float v3 = fmaxf(fmaf(yv.w, scs[c + 3], shs[c + 3]) + xv.w, 0.f);
        acc += v0 * wsh[c] + v1 * wsh[c + 1] + v2 * wsh[c + 2] + v3 * wsh[c + 3];
    }
    out[m] = acc;
}

extern "C" void kernel_launch(void* const* d_in, const int* in_sizes, int n_in,
                              void* d_out, int out_size, void* d_ws, size_t ws_size,
                              hipStream_t stream) {
    if (ws_size < (size_t)WS_FLOATS * 4) return;  // fail visibly (zero output)
    const float* data    = (const float*)d_in[0];
    const float* conv0_w = (const float*)d_in[2];
    const float* bn0_g   = (const float*)d_in[4];
    const float* bn0_b   = (const float*)d_in[5];
    const float* lin_w   = (const float*)d_in[6];
    const float* lin_b   = (const float*)d_in[7];
    const float* res_w1  = (const float*)d_in[8];
    const float* res_g1  = (const float*)d_in[10];
    const float* res_be1 = (const float*)d_in[11];
    const float* res_w2  = (const float*)d_in[12];
    const float* res_g2  = (const float*)d_in[14];
    const float* res_be2 = (const float*)d_in[15];
    float* ws  = (float*)d_ws;
    float* out = (float*)d_out;

    hipMemsetAsync(d_ws, 0, ZERO_CNT * sizeof(float), stream);
    k1_fused<<<dim3(32, 8), 256, 0, stream>>>(data, ws);
    k2_feat<<<dim3(32, 8), 256, 0, stream>>>(data, ws);
    k4_wcat<<<130, 256, 0, stream>>>(conv0_w, ws);
    k3_gram<<<dim3(544, 1, 8), 256, 0, stream>>>(ws);
    ksel<<<4096, 256, 0, stream>>>(ws);
    k5_pq<<<dim3(256, 4), 256, 0, stream>>>(ws);
    k6_bn0stats<<<1024, 256, 0, stream>>>(ws);
    k8_apply<<<2048, 256, 0, stream>>>(ws, bn0_g, bn0_b);

    float* XA = ws + X_OFF;
    float* Y1 = ws + X_OFF + SLOT_SZ;
    float* Y2 = ws + X_OFF + 2 * SLOT_SZ;
    float* XB = ws + XB_OFF;
    float* ST = ws + RESST_OFF;

    // Layer 0 (x0 = XA, materialized by k8)
    k9f_conv<<<dim3(512, 2), 256, 0, stream>>>(XA, res_w1, Y1, ST,
                                               nullptr, nullptr, nullptr, nullptr, nullptr);
    k9f_conv<<<dim3(512, 2), 256, 0, stream>>>(Y1, res_w2, Y2, ST + 2048,
                                               ST, res_g1, res_be1, nullptr, nullptr);
    // Layers 1..3: conv1 consumes (Y2 w/ aff(2i-1), + x_prev), materializes x_i
    float* xcur = XA; float* xnext = XB;
    for (int i = 1; i < 4; ++i) {
        int L = 2 * i, L2 = 2 * i + 1;
        k9f_conv<<<dim3(512, 2), 256, 0, stream>>>(Y2, res_w1 + i * 16384, Y1, ST + L * 2048,
                                                   ST + (L - 1) * 2048,
                                                   res_g2 + (i - 1) * 128, res_be2 + (i - 1) * 128,
                                                   xcur, xnext);
        k9f_conv<<<dim3(512, 2), 256, 0, stream>>>(Y1, res_w2 + i * 16384, Y2, ST + L2 * 2048,
                                                   ST + L * 2048,
                                                   res_g1 + i * 128, res_be1 + i * 128,
                                                   nullptr, nullptr);
        float* t = xcur; xcur = xnext; xnext = t;
    }
    // Final: logit on x4 = relu(aff7(Y2) + x3), x3 is in xcur
    k12_logit<<<64, 256, 0, stream>>>(Y2, xcur, ST + 7 * 2048, res_g2 + 3 * 128, res_be2 + 3 * 128,
                                      lin_w, lin_b, out);
}

// Round 13
// 406.729 us; speedup vs baseline: 1.0258x; 1.0258x over previous
//
#include <hip/hip_runtime.h>
#include <math.h>
#include <float.h>

#define NB 8
#define NC 128
#define NN 2048
#define KNN 20
#define EPSV 1e-5f

// ---- workspace layout (float offsets) ----
#define S_OFF      0            // 1024   (colsum S[b][c])          -- zeroed
#define BN0S_OFF   1024         // 256    (bn0 sum/sumsq)           -- zeroed
#define RESST_OFF  1280         // 16384  (8 layers x [sum1024|sumsq1024]) -- zeroed
#define ZERO_CNT   17664
#define NRM_OFF    17664        // 16384  (per-point sumsq, direct store)
#define SQN_OFF    34048        // 16384
#define F1_OFF     50432        // 16384
#define WCAT_OFF   66816        // 32768  (256 x 128)
#define WCOL_OFF   99584        // 256
#define F128_OFF   99840        // 16384 x 128
#define PQ_OFF     2463232      // 16384 x 256  ([P(128)|Q(128)] per point)
#define X_OFF      6657536      // 3 slots x 2097152 (XA, Y1, Y2)
#define SLOT_SZ    2097152
#define IDX_OFF    12948992     // 327680 ints
#define G_OFF      13276672     // 8 x 2048 x 2048 scores (all batches)
#define XB_OFF     46831104     // second x ping-pong buffer
#define WS_FLOATS  48928256     // 195 MB; d_ws is 256 MiB
// min/max planes (used between k6 and k8 only; Y1/Y2 are dead there)
#define MMN_OFF    (X_OFF + SLOT_SZ)
#define MMX_OFF    (X_OFF + 2 * SLOT_SZ)

// ---- K1: fused per-point sumsq + colsum of data/nrm (one data pass) --------
__launch_bounds__(256)
__global__ void k1_fused(const float* __restrict__ data, float* __restrict__ ws) {
    int b = blockIdx.y;
    int n0 = blockIdx.x * 64;
    int tid = threadIdx.x;
    __shared__ float tile[128][65];     // pad 65: colsum reads 2-way banks
    __shared__ float red[4][64];
    __shared__ float Linv[64];
    int g = tid >> 6, nn = tid & 63;
    const float* dp = data + (size_t)b * NC * NN + n0 + nn;
    float sq = 0.f;
    for (int c = g; c < 128; c += 4) {
        float v = dp[(size_t)c * NN];
        tile[c][nn] = v;
        sq = fmaf(v, v, sq);
    }
    red[g][nn] = sq;
    __syncthreads();
    if (tid < 64) {
        float s = red[0][tid] + red[1][tid] + red[2][tid] + red[3][tid];
        ws[NRM_OFF + b * NN + n0 + tid] = s;
        Linv[tid] = 1.f / (sqrtf(s) + 1e-5f);
    }
    __syncthreads();
    if (tid < 128) {
        float s = 0.f;
#pragma unroll 8
        for (int j = 0; j < 64; ++j) s = fmaf(tile[tid][j], Linv[j], s);
        atomicAdd(&ws[S_OFF + b * NC + tid], s);
    }
}

// ---- K2: F128 (transposed data), f1, sqn -----------------------------------
__launch_bounds__(256)
__global__ void k2_feat(const float* __restrict__ data, float* __restrict__ ws) {
    int b = blockIdx.y;
    int n0 = blockIdx.x * 64;
    int tid = threadIdx.x;
    __shared__ float Sb[NC];
    __shared__ float fT[64][129];       // pad 129: 2-way banks on both phases
    __shared__ float redD[4][64];
    if (tid < NC) Sb[tid] = ws[S_OFF + b * NC + tid];
    __syncthreads();
    int nn = tid & 63, cg = tid >> 6;
    float dotp = 0.f;
    const float* dp = data + (size_t)b * NC * NN + n0 + nn;
    for (int c = cg; c < NC; c += 4) {
        float v = dp[(size_t)c * NN];
        fT[nn][c] = v;
        dotp = fmaf(Sb[c], v, dotp);
    }
    redD[cg][nn] = dotp;
    __syncthreads();
    if (tid < 64) {
        float dt = redD[0][tid] + redD[1][tid] + redD[2][tid] + redD[3][tid];
        float nrmsq = ws[NRM_OFF + b * NN + n0 + tid];
        float nrm = sqrtf(nrmsq) + 1e-5f;
        float D = (dt / nrm - 1.f) * (1.f / (float)NN);
        float f1 = tanhf(D); if (f1 < 0.f) f1 = 0.f;
        ws[F1_OFF + b * NN + n0 + tid] = f1;
        ws[SQN_OFF + b * NN + n0 + tid] = nrmsq + f1 * f1;
    }
    __syncthreads();
    float* out = ws + F128_OFF + (size_t)(b * NN + n0) * 128;
    for (int i = tid; i < 64 * 128; i += 256) out[i] = fT[i >> 7][i & 127];
}

// ---- K4: Wcat128[256][128] = [W1+W2 ; W2] cols 0..127; wcol = column 128 ---
__launch_bounds__(256)
__global__ void k4_wcat(const float* __restrict__ w, float* __restrict__ ws) {
    int i = blockIdx.x * 256 + threadIdx.x;
    if (i < 32768) {
        int o = i >> 7, c = i & 127;
        float v = (o < 128) ? w[o * 258 + c] + w[o * 258 + 129 + c]
                            : w[(o - 128) * 258 + 129 + c];
        ws[WCAT_OFF + i] = v;
    } else if (i < 33024) {
        int o = i - 32768;
        float v = (o < 128) ? w[o * 258 + 128] + w[o * 258 + 257]
                            : w[(o - 128) * 258 + 257];
        ws[WCOL_OFF + o] = v;
    }
}

// ------- K3: G[b][n][m] = 2*(X_n.X_m + f1_n*f1_m) - sq[m], K=128 ------------
// Symmetric triangular pairs split into n-halves: 64(n) x 128(m) per block,
// acc[4][8], grid 272x8. Off-diagonal blocks also write the transposed stripe.
__launch_bounds__(256)
__global__ void k3_gram(float* __restrict__ ws) {
    __shared__ __align__(16) float As[8][64];
    __shared__ __align__(16) float Bs[8][128];
    int tid = threadIdx.x;
    int b = blockIdx.z;
    int p = blockIdx.x >> 1, half = blockIdx.x & 1;
    int a = 0, rem = 16;
    while (p >= rem) { p -= rem; ++a; --rem; }
    int bq = a + p;                      // a <= bq
    int n0 = a * 128 + half * 64, m0 = bq * 128;
    const float* F = ws + F128_OFF + (size_t)b * NN * 128;
    float acc[4][8];
#pragma unroll
    for (int i = 0; i < 4; ++i)
#pragma unroll
        for (int j = 0; j < 8; ++j) acc[i][j] = 0.f;
    int rr = tid >> 1, cq = tid & 1;     // B staging: 128 rows x 2 k-halves
    int ar = (tid & 127) >> 1, acq = tid & 1; // A staging (tid<128): 64 rows
    int tx = tid & 15, ty = tid >> 4;
    for (int kc = 0; kc < 128; kc += 8) {
        float4 bv = *(const float4*)&F[(size_t)(m0 + rr) * 128 + kc + cq * 4];
        float4 av;
        if (tid < 128) av = *(const float4*)&F[(size_t)(n0 + ar) * 128 + kc + acq * 4];
        __syncthreads();
        Bs[cq*4+0][rr] = bv.x; Bs[cq*4+1][rr] = bv.y; Bs[cq*4+2][rr] = bv.z; Bs[cq*4+3][rr] = bv.w;
        if (tid < 128) {
            As[acq*4+0][ar] = av.x; As[acq*4+1][ar] = av.y;
            As[acq*4+2][ar] = av.z; As[acq*4+3][ar] = av.w;
        }
        __syncthreads();
#pragma unroll
        for (int kk = 0; kk < 8; ++kk) {
            float aa[4], bb[8];
            *(float4*)&aa[0] = *(const float4*)&As[kk][ty * 4];
            *(float4*)&bb[0] = *(const float4*)&Bs[kk][tx * 4];
            *(float4*)&bb[4] = *(const float4*)&Bs[kk][64 + tx * 4];
#pragma unroll
            for (int i = 0; i < 4; ++i)
#pragma unroll
                for (int j = 0; j < 8; ++j) acc[i][j] = fmaf(aa[i], bb[j], acc[i][j]);
        }
    }
    const float* F1 = ws + F1_OFF + b * NN;
    const float* SQ = ws + SQN_OFF + b * NN;
    float sqv[8], f1m[8], sqn[4], f1nv[4];
#pragma unroll
    for (int j = 0; j < 4; ++j) {
        sqv[j]     = SQ[m0 + tx * 4 + j];
        sqv[4 + j] = SQ[m0 + 64 + tx * 4 + j];
        f1m[j]     = F1[m0 + tx * 4 + j];
        f1m[4 + j] = F1[m0 + 64 + tx * 4 + j];
    }
#pragma unroll
    for (int i = 0; i < 4; ++i) {
        int n = n0 + ty * 4 + i;
        sqn[i]  = SQ[n];
        f1nv[i] = F1[n];
    }
    float* G = ws + G_OFF + (size_t)b * NN * NN;
    // normal write: rows n-range (64), cols m-range (128), minus sq[m]
#pragma unroll
    for (int i = 0; i < 4; ++i) {
        int row = n0 + ty * 4 + i;
        float f1n = f1nv[i];
        float4 o1, o2;
        o1.x = 2.f*fmaf(f1n, f1m[0], acc[i][0]) - sqv[0];
        o1.y = 2.f*fmaf(f1n, f1m[1], acc[i][1]) - sqv[1];
        o1.z = 2.f*fmaf(f1n, f1m[2], acc[i][2]) - sqv[2];
        o1.w = 2.f*fmaf(f1n, f1m[3], acc[i][3]) - sqv[3];
        o2.x = 2.f*fmaf(f1n, f1m[4], acc[i][4]) - sqv[4];
        o2.y = 2.f*fmaf(f1n, f1m[5], acc[i][5]) - sqv[5];
        o2.z = 2.f*fmaf(f1n, f1m[6], acc[i][6]) - sqv[6];
        o2.w = 2.f*fmaf(f1n, f1m[7], acc[i][7]) - sqv[7];
        *(float4*)&G[(size_t)row * NN + m0 + tx * 4]      = o1;
        *(float4*)&G[(size_t)row * NN + m0 + 64 + tx * 4] = o2;
    }
    if (a != bq) {
        // transposed write: rows m-range (128), cols n-range (64), minus sq[n]
#pragma unroll
        for (int j = 0; j < 8; ++j) {
            int cl = (j < 4) ? (tx * 4 + j) : (64 + tx * 4 + (j - 4));
            size_t grow = (size_t)(m0 + cl) * NN + n0 + ty * 4;
            float f1mj = f1m[j];
            float4 t0;
            t0.x = 2.f*fmaf(f1nv[0], f1mj, acc[0][j]) - sqn[0];
            t0.y = 2.f*fmaf(f1nv[1], f1mj, acc[1][j]) - sqn[1];
            t0.z = 2.f*fmaf(f1nv[2], f1mj, acc[2][j]) - sqn[2];
            t0.w = 2.f*fmaf(f1nv[3], f1mj, acc[3][j]) - sqn[3];
            *(float4*)&G[grow] = t0;
        }
    }
}

// ------- KSEL: per-row top-21 (drop first = self) -> idx[20], all batches ---
// float4 loads; slot i of lane l = column l*32+i. Exact top_k tie semantics.
__launch_bounds__(256)
__global__ void ksel(float* __restrict__ ws) {
    int wid = threadIdx.x >> 6, lane = threadIdx.x & 63;
    int r = blockIdx.x * 4 + wid;            // global row 0..16383 (= b*2048+n)
    const float* row = ws + G_OFF + (size_t)r * NN;
    float v[32];
#pragma unroll
    for (int i = 0; i < 8; ++i)
        *(float4*)&v[i * 4] = *(const float4*)&row[lane * 32 + i * 4];
    float b1v = -FLT_MAX, b2v = -FLT_MAX;
    int b1i = 0, b2i = 0;
#pragma unroll
    for (int i = 0; i < 32; ++i) {
        float x = v[i];
        if (x > b1v)      { b2v = b1v; b2i = b1i; b1v = x; b1i = i; }
        else if (x > b2v) { b2v = x; b2i = i; }
    }
    unsigned int mask = 0u;
    bool has2 = true;
    int* out = (int*)(ws + IDX_OFF) + (size_t)r * KNN;
    for (int k = 0; k < 21; ++k) {
        float M = b1v;
#pragma unroll
        for (int off = 1; off < 64; off <<= 1) M = fmaxf(M, __shfl_xor(M, off));
        unsigned long long tied = __ballot(b1v == M);
        int mm;
        if (__popcll(tied) > 1) {
            int cand = (b1v == M) ? ((lane << 5) | b1i) : 0x7FFFFFFF;
#pragma unroll
            for (int off = 1; off < 64; off <<= 1) {
                int oc = __shfl_xor(cand, off);
                cand = oc < cand ? oc : cand;
            }
            mm = cand;
        } else {
            int l = __ffsll(tied) - 1;
            mm = (l << 5) | __shfl(b1i, l);
        }
        if (k > 0 && lane == 0) out[k - 1] = mm;
        if (lane == (mm >> 5)) {
            mask |= 1u << b1i;
            if (has2) { b1v = b2v; b1i = b2i; has2 = false; }
            else {
                b1v = -FLT_MAX; b2v = -FLT_MAX; b1i = 0; b2i = 0;
#pragma unroll
                for (int i = 0; i < 32; ++i) {
                    float x = (mask & (1u << i)) ? -FLT_MAX : v[i];
                    if (x > b1v)      { b2v = b1v; b2i = b1i; b1v = x; b1i = i; }
                    else if (x > b2v) { b2v = x; b2i = i; }
                }
                has2 = true;
            }
        }
    }
}

// ---- K5: PQ[m][256] = F128[m][128] x Wcat128^T + f1[m]*wcol ---------------
__launch_bounds__(256)
__global__ void k5_pq(float* __restrict__ ws) {
    __shared__ __align__(16) float As[16][64];
    __shared__ __align__(16) float Bs[16][64];
    int tid = threadIdx.x;
    int m0 = blockIdx.x * 64, o0 = blockIdx.y * 64;
    int rr = tid >> 2, cq = tid & 3;
    int tx = tid & 15, ty = tid >> 4;
    float acc[4][4];
#pragma unroll
    for (int i = 0; i < 4; ++i)
#pragma unroll
        for (int j = 0; j < 4; ++j) acc[i][j] = 0.f;
    const float* F  = ws + F128_OFF;
    const float* Wc = ws + WCAT_OFF;
    for (int kc = 0; kc < 128; kc += 16) {
        float4 av = *(const float4*)&F [(size_t)(m0 + rr) * 128 + kc + cq * 4];
        float4 bv = *(const float4*)&Wc[(size_t)(o0 + rr) * 128 + kc + cq * 4];
        __syncthreads();
        As[cq*4+0][rr]=av.x; As[cq*4+1][rr]=av.y; As[cq*4+2][rr]=av.z; As[cq*4+3][rr]=av.w;
        Bs[cq*4+0][rr]=bv.x; Bs[cq*4+1][rr]=bv.y; Bs[cq*4+2][rr]=bv.z; Bs[cq*4+3][rr]=bv.w;
        __syncthreads();
#pragma unroll
        for (int kk = 0; kk < 16; ++kk) {
            float a[4], bb[4];
            *(float4*)&a[0]  = *(const float4*)&As[kk][ty * 4];
            *(float4*)&bb[0] = *(const float4*)&Bs[kk][tx * 4];
#pragma unroll
            for (int i = 0; i < 4; ++i)
#pragma unroll
                for (int j = 0; j < 4; ++j) acc[i][j] = fmaf(a[i], bb[j], acc[i][j]);
        }
    }
    float wc[4], f1v[4];
#pragma unroll
    for (int j = 0; j < 4; ++j) {
        wc[j]  = ws[WCOL_OFF + o0 + tx * 4 + j];
        f1v[j] = ws[F1_OFF + m0 + ty * 4 + j];
    }
#pragma unroll
    for (int i = 0; i < 4; ++i) {
        float4 o;
        o.x = fmaf(f1v[i], wc[0], acc[i][0]);
        o.y = fmaf(f1v[i], wc[1], acc[i][1]);
        o.z = fmaf(f1v[i], wc[2], acc[i][2]);
        o.w = fmaf(f1v[i], wc[3], acc[i][3]);
        *(float4*)&ws[PQ_OFF + (size_t)(m0 + ty * 4 + i) * 256 + o0 + tx * 4] = o;
    }
}

// -------- K6: bn0 stats + per-(m,o) min/max of (P - Q[j]) over neighbors ----
__launch_bounds__(256)
__global__ void k6_bn0stats(float* __restrict__ ws) {
    int tid = threadIdx.x;
    int o = tid & 127, h = tid >> 7;
    int m0 = blockIdx.x * 16;
    const float* PQ = ws + PQ_OFF;
    const int* idx = (const int*)(ws + IDX_OFF);
    float* MMn = ws + MMN_OFF;
    float* MMx = ws + MMX_OFF;
    __shared__ float red[2][128];
    float s = 0.f, q = 0.f;
    for (int p = h; p < 16; p += 2) {
        int m = m0 + p;
        int bb = m >> 11;
        float pv = PQ[(size_t)m * 256 + o];
        const int* ip = idx + (size_t)m * KNN;
        float mn = FLT_MAX, mx = -FLT_MAX;
        for (int k = 0; k < KNN; ++k) {
            int j = ip[k];
            float val = pv - PQ[(size_t)(bb * NN + j) * 256 + 128 + o];
            s += val; q += val * val;
            mn = fminf(mn, val); mx = fmaxf(mx, val);
        }
        MMn[(size_t)m * NC + o] = mn;
        MMx[(size_t)m * NC + o] = mx;
    }
    red[h][o] = s; __syncthreads();
    if (tid < 128) atomicAdd(&ws[BN0S_OFF + tid], red[0][tid] + red[1][tid]);
    __syncthreads();
    red[h][o] = q; __syncthreads();
    if (tid < 128) atomicAdd(&ws[BN0S_OFF + 128 + tid], red[0][tid] + red[1][tid]);
}

// ---- K8: X0 = relu(sc * (sc>0 ? max : min) + sh); affine derived inline ----
__launch_bounds__(256)
__global__ void k8_apply(float* __restrict__ ws, const float* __restrict__ g,
                         const float* __restrict__ be) {
    int e = blockIdx.x * 256 + threadIdx.x;
    int fi = e * 4;
    int o = fi & 127;
    const float cnt = 1.f / (float)(NB * NN * KNN);
    float4 sum4 = *(const float4*)&ws[BN0S_OFF + o];
    float4 ssq4 = *(const float4*)&ws[BN0S_OFF + 128 + o];
    float4 g4   = *(const float4*)&g[o];
    float4 be4  = *(const float4*)&be[o];
    float4 mn = *(const float4*)&ws[MMN_OFF + fi];
    float4 mx = *(const float4*)&ws[MMX_OFF + fi];
    float4 r;
#define BN0_DO(comp) { \
    float m_ = sum4.comp * cnt; \
    float v_ = ssq4.comp * cnt - m_ * m_; if (v_ < 0.f) v_ = 0.f; \
    float sc_ = g4.comp * rsqrtf(v_ + EPSV); \
    float sh_ = be4.comp - m_ * sc_; \
    r.comp = fmaxf(fmaf(sc_ > 0.f ? mx.comp : mn.comp, sc_, sh_), 0.f); }
    BN0_DO(x) BN0_DO(y) BN0_DO(z) BN0_DO(w)
#undef BN0_DO
    *(float4*)&ws[X_OFF + fi] = r;
}

// ---- K9f: res conv GEMM (32m x 64o tiles) + fused per-(b,o) stats.
// If statsIn: derive per-(block-batch) inorm+bn affine from raw stats;
// input t = relu(x*sc + sh [+ xin]). If xw && blockIdx.y==0: write t back.
__launch_bounds__(256)
__global__ void k9f_conv(const float* __restrict__ x, const float* __restrict__ w,
                         float* __restrict__ y, float* __restrict__ stats,
                         const float* __restrict__ statsIn,
                         const float* __restrict__ g, const float* __restrict__ be,
                         const float* __restrict__ xin, float* __restrict__ xw) {
    __shared__ __align__(16) float As[16][32];
    __shared__ __align__(16) float Bs[16][64];
    __shared__ float red[16][64];
    __shared__ float vvv[8][128];
    __shared__ float scs[128], shs[128];
    int tid = threadIdx.x;
    int m0 = blockIdx.x * 32, o0 = blockIdx.y * 64;
    int bA = m0 >> 11;                       // whole block is one batch (32 | 2048)
    if (statsIn) {
        for (int e = tid; e < 1024; e += 256) {
            float sum = statsIn[e], ssq = statsIn[1024 + e];
            float m_ = sum * (1.f / (float)NN);
            float v_ = ssq * (1.f / (float)NN) - m_ * m_; if (v_ < 0.f) v_ = 0.f;
            vvv[e >> 7][e & 127] = v_ / (v_ + EPSV);
        }
        __syncthreads();
        if (tid < 128) {
            float a = 0.f;
#pragma unroll
            for (int b2 = 0; b2 < NB; ++b2) a += vvv[b2][tid];
            float rsbn = rsqrtf(a * (1.f / (float)NB) + EPSV);
            float sum = statsIn[bA * 128 + tid], ssq = statsIn[1024 + bA * 128 + tid];
            float m_ = sum * (1.f / (float)NN);
            float v_ = ssq * (1.f / (float)NN) - m_ * m_; if (v_ < 0.f) v_ = 0.f;
            float sc_ = rsqrtf(v_ + EPSV) * rsbn * g[tid];
            scs[tid] = sc_;
            shs[tid] = be[tid] - m_ * sc_;
        }
        __syncthreads();
    }
    int rr = tid >> 2, cq = tid & 3;              // B staging: 64 rows x 4 chunks
    int ar = (tid & 127) >> 2, acq = tid & 3;     // A staging (tid<128): 32 rows
    int tx = tid & 15, ty = tid >> 4;
    float acc[2][4];
#pragma unroll
    for (int i = 0; i < 2; ++i)
#pragma unroll
        for (int j = 0; j < 4; ++j) acc[i][j] = 0.f;
    for (int kc = 0; kc < NC; kc += 16) {
        float4 av;
        if (tid < 128) {
            av = *(const float4*)&x[(size_t)(m0 + ar) * NC + kc + acq * 4];
            if (statsIn) {
                int c = kc + acq * 4;
                av.x = fmaf(av.x, scs[c],     shs[c]);
                av.y = fmaf(av.y, scs[c + 1], shs[c + 1]);
                av.z = fmaf(av.z, scs[c + 2], shs[c + 2]);
                av.w = fmaf(av.w, scs[c + 3], shs[c + 3]);
                if (xin) {
                    float4 xv = *(const float4*)&xin[(size_t)(m0 + ar) * NC + kc + acq * 4];
                    av.x += xv.x; av.y += xv.y; av.z += xv.z; av.w += xv.w;
                }
                av.x = fmaxf(av.x, 0.f); av.y = fmaxf(av.y, 0.f);
                av.z = fmaxf(av.z, 0.f); av.w = fmaxf(av.w, 0.f);
                if (xw && blockIdx.y == 0)
                    *(float4*)&xw[(size_t)(m0 + ar) * NC + kc + acq * 4] = av;
            }
        }
        float4 bv = *(const float4*)&w[(size_t)(o0 + rr) * NC + kc + cq * 4];
        __syncthreads();
        if (tid < 128) {
            As[acq*4+0][ar]=av.x; As[acq*4+1][ar]=av.y;
            As[acq*4+2][ar]=av.z; As[acq*4+3][ar]=av.w;
        }
        Bs[cq*4+0][rr]=bv.x; Bs[cq*4+1][rr]=bv.y; Bs[cq*4+2][rr]=bv.z; Bs[cq*4+3][rr]=bv.w;
        __syncthreads();
#pragma unroll
        for (int kk = 0; kk < 16; ++kk) {
            float a0 = As[kk][ty * 2], a1 = As[kk][ty * 2 + 1];
            float bb[4];
            *(float4*)&bb[0] = *(const float4*)&Bs[kk][tx * 4];
#pragma unroll
            for (int j = 0; j < 4; ++j) {
                acc[0][j] = fmaf(a0, bb[j], acc[0][j]);
                acc[1][j] = fmaf(a1, bb[j], acc[1][j]);
            }
        }
    }
#pragma unroll
    for (int i = 0; i < 2; ++i) {
        float4 o;
        o.x = acc[i][0]; o.y = acc[i][1]; o.z = acc[i][2]; o.w = acc[i][3];
        *(float4*)&y[(size_t)(m0 + ty * 2 + i) * NC + o0 + tx * 4] = o;
    }
    float s[4], q[4];
#pragma unroll
    for (int j = 0; j < 4; ++j) {
        s[j] = acc[0][j] + acc[1][j];
        q[j] = acc[0][j]*acc[0][j] + acc[1][j]*acc[1][j];
    }
    *(float4*)&red[ty][tx * 4] = make_float4(s[0], s[1], s[2], s[3]);
    __syncthreads();
    if (tid < 64) {
        float t = 0.f;
#pragma unroll
        for (int g2 = 0; g2 < 16; ++g2) t += red[g2][tid];
        atomicAdd(&stats[bA * NC + o0 + tid], t);
    }
    __syncthreads();
    *(float4*)&red[ty][tx * 4] = make_float4(q[0], q[1], q[2], q[3]);
    __syncthreads();
    if (tid < 64) {
        float t = 0.f;
#pragma unroll
        for (int g2 = 0; g2 < 16; ++g2) t += red[g2][tid];
        atomicAdd(&stats[1024 + bA * NC + o0 + tid], t);
    }
}

// ---- K12: logit = lin_w . relu(aff7(y2) + xin) + lin_b; aff derived inline -
__launch_bounds__(256)
__global__ void k12_logit(const float* __restrict__ y2, const float* __restrict__ xin,
                          const float* __restrict__ statsIn,
                          const float* __restrict__ g, const float* __restrict__ be,
                          const float* __restrict__ lw, const float* __restrict__ lb,
                          float* __restrict__ out) {
    __shared__ float wsh[128];
    __shared__ float vvv[8][128];
    __shared__ float scs[128], shs[128];
    int tid = threadIdx.x;
    int b = (blockIdx.x * 256) >> 11;        // whole block one batch (256 | 2048)
    if (tid < 128) wsh[tid] = lw[tid];
    for (int e = tid; e < 1024; e += 256) {
        float sum = statsIn[e], ssq = statsIn[1024 + e];
        float m_ = sum * (1.f / (float)NN);
        float v_ = ssq * (1.f / (float)NN) - m_ * m_; if (v_ < 0.f) v_ = 0.f;
        vvv[e >> 7][e & 127] = v_ / (v_ + EPSV);
    }
    __syncthreads();
    if (tid < 128) {
        float a = 0.f;
#pragma unroll
        for (int b2 = 0; b2 < NB; ++b2) a += vvv[b2][tid];
        float rsbn = rsqrtf(a * (1.f / (float)NB) + EPSV);
        float sum = statsIn[b * 128 + tid], ssq = statsIn[1024 + b * 128 + tid];
        float m_ = sum * (1.f / (float)NN);
        float v_ = ssq * (1.f / (float)NN) - m_ * m_; if (v_ < 0.f) v_ = 0.f;
        float sc_ = rsqrtf(v_ + EPSV) * rsbn * g[tid];
        scs[tid] = sc_;
        shs[tid] = be[tid] - m_ * sc_;
    }
    __syncthreads();
    int m = blockIdx.x * 256 + tid;
    const float* yp = y2 + (size_t)m * NC;
    const float* xp = xin + (size_t)m * NC;
    float acc = lb[0];
    for (int c = 0; c < NC; c += 4) {
        float4 yv = *(const float4*)&yp[c];
        float4 xv = *(const float4*)&xp[c];
        float v0 = fmaxf(fmaf(yv.x, scs[c],     shs[c])     + xv.x, 0.f);
        float v1 = fmaxf(fmaf(yv.y, scs[c + 1], shs[c + 1]) + xv.y, 0.f);
        float v2 = fmaxf(fmaf(yv.z, scs[c + 2], shs[c + 2]) + xv.z, 0.f);
        float v3 = fmaxf(fmaf(yv.w, scs[c + 3], shs[c + 3]) + xv.w, 0.f);
        acc += v0 * wsh[c] + v1 * wsh[c + 1] + v2 * wsh[c + 2] + v3 * wsh[c + 3];
    }
    out[m] = acc;
}

extern "C" void kernel_launch(void* const* d_in, const int* in_sizes, int n_in,
                              void* d_out, int out_size, void* d_ws, size_t ws_size,
                              hipStream_t stream) {
    if (ws_size < (size_t)WS_FLOATS * 4) return;  // fail visibly (zero output)
    const float* data    = (const float*)d_in[0];
    const float* conv0_w = (const float*)d_in[2];
    const float* bn0_g   = (const float*)d_in[4];
    const float* bn0_b   = (const float*)d_in[5];
    const float* lin_w   = (const float*)d_in[6];
    const float* lin_b   = (const float*)d_in[7];
    const float* res_w1  = (const float*)d_in[8];
    const float* res_g1  = (const float*)d_in[10];
    const float* res_be1 = (const float*)d_in[11];
    const float* res_w2  = (const float*)d_in[12];
    const float* res_g2  = (const float*)d_in[14];
    const float* res_be2 = (const float*)d_in[15];
    float* ws  = (float*)d_ws;
    float* out = (float*)d_out;

    hipMemsetAsync(d_ws, 0, ZERO_CNT * sizeof(float), stream);
    k1_fused<<<dim3(32, 8), 256, 0, stream>>>(data, ws);
    k2_feat<<<dim3(32, 8), 256, 0, stream>>>(data, ws);
    k4_wcat<<<130, 256, 0, stream>>>(conv0_w, ws);
    k3_gram<<<dim3(272, 1, 8), 256, 0, stream>>>(ws);
    ksel<<<4096, 256, 0, stream>>>(ws);
    k5_pq<<<dim3(256, 4), 256, 0, stream>>>(ws);
    k6_bn0stats<<<1024, 256, 0, stream>>>(ws);
    k8_apply<<<2048, 256, 0, stream>>>(ws, bn0_g, bn0_b);

    float* XA = ws + X_OFF;
    float* Y1 = ws + X_OFF + SLOT_SZ;
    float* Y2 = ws + X_OFF + 2 * SLOT_SZ;
    float* XB = ws + XB_OFF;
    float* ST = ws + RESST_OFF;

    // Layer 0 (x0 = XA, materialized by k8)
    k9f_conv<<<dim3(512, 2), 256, 0, stream>>>(XA, res_w1, Y1, ST,
                                               nullptr, nullptr, nullptr, nullptr, nullptr);
    k9f_conv<<<dim3(512, 2), 256, 0, stream>>>(Y1, res_w2, Y2, ST + 2048,
                                               ST, res_g1, res_be1, nullptr, nullptr);
    // Layers 1..3: conv1 consumes (Y2 w/ aff(2i-1), + x_prev), materializes x_i
    float* xcur = XA; float* xnext = XB;
    for (int i = 1; i < 4; ++i) {
        int L = 2 * i, L2 = 2 * i + 1;
        k9f_conv<<<dim3(512, 2), 256, 0, stream>>>(Y2, res_w1 + i * 16384, Y1, ST + L * 2048,
                                                   ST + (L - 1) * 2048,
                                                   res_g2 + (i - 1) * 128, res_be2 + (i - 1) * 128,
                                                   xcur, xnext);
        k9f_conv<<<dim3(512, 2), 256, 0, stream>>>(Y1, res_w2 + i * 16384, Y2, ST + L2 * 2048,
                                                   ST + L * 2048,
                                                   res_g1 + i * 128, res_be1 + i * 128,
                                                   nullptr, nullptr);
        float* t = xcur; xcur = xnext; xnext = t;
    }
    // Final: logit on x4 = relu(aff7(Y2) + x3), x3 is in xcur
    k12_logit<<<64, 256, 0, stream>>>(Y2, xcur, ST + 7 * 2048, res_g2 + 3 * 128, res_be2 + 3 * 128,
                                      lin_w, lin_b, out);
}

// Round 14
// 372.476 us; speedup vs baseline: 1.1201x; 1.0920x over previous
//
#include <hip/hip_runtime.h>
#include <math.h>
#include <float.h>

#define NB 8
#define NC 128
#define NN 2048
#define KNN 20
#define EPSV 1e-5f

// ---- workspace layout (float offsets) ----
#define S_OFF      0            // 1024   (colsum S[b][c])          -- zeroed
#define BN0S_OFF   1024         // 256    (bn0 sum/sumsq)           -- zeroed
#define RESST_OFF  1280         // 16384  (8 layers x [sum1024|sumsq1024]) -- zeroed
#define ZERO_CNT   17664
#define NRM_OFF    17664        // 16384  (per-point sumsq, direct store)
#define SQN_OFF    34048        // 16384
#define F1_OFF     50432        // 16384
#define WCAT_OFF   66816        // 32768  (256 x 128)
#define WCOL_OFF   99584        // 256
#define F128_OFF   99840        // 16384 x 128
#define PQ_OFF     2463232      // 16384 x 256  ([P(128)|Q(128)] per point)
#define X_OFF      6657536      // 3 slots x 2097152 (XA, Y1, Y2)
#define SLOT_SZ    2097152
#define IDX_OFF    12948992     // 327680 ints
#define G_OFF      13276672     // 8 x 2048 x 2048 scores (all batches)
#define XB_OFF     46831104     // second x ping-pong buffer
#define WS_FLOATS  48928256     // 195 MB; d_ws is 256 MiB
// min/max planes (used between k6 and k8 only; Y1/Y2 are dead there)
#define MMN_OFF    (X_OFF + SLOT_SZ)
#define MMX_OFF    (X_OFF + 2 * SLOT_SZ)

// ---- K1: fused per-point sumsq + colsum of data/nrm (one data pass) --------
__launch_bounds__(256)
__global__ void k1_fused(const float* __restrict__ data, float* __restrict__ ws) {
    int b = blockIdx.y;
    int n0 = blockIdx.x * 64;
    int tid = threadIdx.x;
    __shared__ float tile[128][65];     // pad 65: colsum reads 2-way banks
    __shared__ float red[4][64];
    __shared__ float Linv[64];
    int g = tid >> 6, nn = tid & 63;
    const float* dp = data + (size_t)b * NC * NN + n0 + nn;
    float sq = 0.f;
    for (int c = g; c < 128; c += 4) {
        float v = dp[(size_t)c * NN];
        tile[c][nn] = v;
        sq = fmaf(v, v, sq);
    }
    red[g][nn] = sq;
    __syncthreads();
    if (tid < 64) {
        float s = red[0][tid] + red[1][tid] + red[2][tid] + red[3][tid];
        ws[NRM_OFF + b * NN + n0 + tid] = s;
        Linv[tid] = 1.f / (sqrtf(s) + 1e-5f);
    }
    __syncthreads();
    if (tid < 128) {
        float s = 0.f;
#pragma unroll 8
        for (int j = 0; j < 64; ++j) s = fmaf(tile[tid][j], Linv[j], s);
        atomicAdd(&ws[S_OFF + b * NC + tid], s);
    }
}

// ---- K2: F128 (transposed data), f1, sqn -----------------------------------
__launch_bounds__(256)
__global__ void k2_feat(const float* __restrict__ data, float* __restrict__ ws) {
    int b = blockIdx.y;
    int n0 = blockIdx.x * 64;
    int tid = threadIdx.x;
    __shared__ float Sb[NC];
    __shared__ float fT[64][129];       // pad 129: 2-way banks on both phases
    __shared__ float redD[4][64];
    if (tid < NC) Sb[tid] = ws[S_OFF + b * NC + tid];
    __syncthreads();
    int nn = tid & 63, cg = tid >> 6;
    float dotp = 0.f;
    const float* dp = data + (size_t)b * NC * NN + n0 + nn;
    for (int c = cg; c < NC; c += 4) {
        float v = dp[(size_t)c * NN];
        fT[nn][c] = v;
        dotp = fmaf(Sb[c], v, dotp);
    }
    redD[cg][nn] = dotp;
    __syncthreads();
    if (tid < 64) {
        float dt = redD[0][tid] + redD[1][tid] + redD[2][tid] + redD[3][tid];
        float nrmsq = ws[NRM_OFF + b * NN + n0 + tid];
        float nrm = sqrtf(nrmsq) + 1e-5f;
        float D = (dt / nrm - 1.f) * (1.f / (float)NN);
        float f1 = tanhf(D); if (f1 < 0.f) f1 = 0.f;
        ws[F1_OFF + b * NN + n0 + tid] = f1;
        ws[SQN_OFF + b * NN + n0 + tid] = nrmsq + f1 * f1;
    }
    __syncthreads();
    float* out = ws + F128_OFF + (size_t)(b * NN + n0) * 128;
    for (int i = tid; i < 64 * 128; i += 256) out[i] = fT[i >> 7][i & 127];
}

// ---- K4: Wcat128[256][128] = [W1+W2 ; W2] cols 0..127; wcol = column 128 ---
__launch_bounds__(256)
__global__ void k4_wcat(const float* __restrict__ w, float* __restrict__ ws) {
    int i = blockIdx.x * 256 + threadIdx.x;
    if (i < 32768) {
        int o = i >> 7, c = i & 127;
        float v = (o < 128) ? w[o * 258 + c] + w[o * 258 + 129 + c]
                            : w[(o - 128) * 258 + 129 + c];
        ws[WCAT_OFF + i] = v;
    } else if (i < 33024) {
        int o = i - 32768;
        float v = (o < 128) ? w[o * 258 + 128] + w[o * 258 + 257]
                            : w[(o - 128) * 258 + 257];
        ws[WCOL_OFF + o] = v;
    }
}

// ------- K3: G[b][n][m] = 2*(X_n.X_m + f1_n*f1_m) - sq[m], K=128 ------------
// Symmetric triangular pairs split into n-halves: 64(n) x 128(m) per block,
// acc[4][8], grid 272x8. Off-diagonal blocks also write the transposed stripe.
__launch_bounds__(256)
__global__ void k3_gram(float* __restrict__ ws) {
    __shared__ __align__(16) float As[8][64];
    __shared__ __align__(16) float Bs[8][128];
    int tid = threadIdx.x;
    int b = blockIdx.z;
    int p = blockIdx.x >> 1, half = blockIdx.x & 1;
    int a = 0, rem = 16;
    while (p >= rem) { p -= rem; ++a; --rem; }
    int bq = a + p;                      // a <= bq
    int n0 = a * 128 + half * 64, m0 = bq * 128;
    const float* F = ws + F128_OFF + (size_t)b * NN * 128;
    float acc[4][8];
#pragma unroll
    for (int i = 0; i < 4; ++i)
#pragma unroll
        for (int j = 0; j < 8; ++j) acc[i][j] = 0.f;
    int rr = tid >> 1, cq = tid & 1;     // B staging: 128 rows x 2 k-halves
    int ar = (tid & 127) >> 1, acq = tid & 1; // A staging (tid<128): 64 rows
    int tx = tid & 15, ty = tid >> 4;
    for (int kc = 0; kc < 128; kc += 8) {
        float4 bv = *(const float4*)&F[(size_t)(m0 + rr) * 128 + kc + cq * 4];
        float4 av;
        if (tid < 128) av = *(const float4*)&F[(size_t)(n0 + ar) * 128 + kc + acq * 4];
        __syncthreads();
        Bs[cq*4+0][rr] = bv.x; Bs[cq*4+1][rr] = bv.y; Bs[cq*4+2][rr] = bv.z; Bs[cq*4+3][rr] = bv.w;
        if (tid < 128) {
            As[acq*4+0][ar] = av.x; As[acq*4+1][ar] = av.y;
            As[acq*4+2][ar] = av.z; As[acq*4+3][ar] = av.w;
        }
        __syncthreads();
#pragma unroll
        for (int kk = 0; kk < 8; ++kk) {
            float aa[4], bb[8];
            *(float4*)&aa[0] = *(const float4*)&As[kk][ty * 4];
            *(float4*)&bb[0] = *(const float4*)&Bs[kk][tx * 4];
            *(float4*)&bb[4] = *(const float4*)&Bs[kk][64 + tx * 4];
#pragma unroll
            for (int i = 0; i < 4; ++i)
#pragma unroll
                for (int j = 0; j < 8; ++j) acc[i][j] = fmaf(aa[i], bb[j], acc[i][j]);
        }
    }
    const float* F1 = ws + F1_OFF + b * NN;
    const float* SQ = ws + SQN_OFF + b * NN;
    float sqv[8], f1m[8], sqn[4], f1nv[4];
#pragma unroll
    for (int j = 0; j < 4; ++j) {
        sqv[j]     = SQ[m0 + tx * 4 + j];
        sqv[4 + j] = SQ[m0 + 64 + tx * 4 + j];
        f1m[j]     = F1[m0 + tx * 4 + j];
        f1m[4 + j] = F1[m0 + 64 + tx * 4 + j];
    }
#pragma unroll
    for (int i = 0; i < 4; ++i) {
        int n = n0 + ty * 4 + i;
        sqn[i]  = SQ[n];
        f1nv[i] = F1[n];
    }
    float* G = ws + G_OFF + (size_t)b * NN * NN;
    // normal write: rows n-range (64), cols m-range (128), minus sq[m]
#pragma unroll
    for (int i = 0; i < 4; ++i) {
        int row = n0 + ty * 4 + i;
        float f1n = f1nv[i];
        float4 o1, o2;
        o1.x = 2.f*fmaf(f1n, f1m[0], acc[i][0]) - sqv[0];
        o1.y = 2.f*fmaf(f1n, f1m[1], acc[i][1]) - sqv[1];
        o1.z = 2.f*fmaf(f1n, f1m[2], acc[i][2]) - sqv[2];
        o1.w = 2.f*fmaf(f1n, f1m[3], acc[i][3]) - sqv[3];
        o2.x = 2.f*fmaf(f1n, f1m[4], acc[i][4]) - sqv[4];
        o2.y = 2.f*fmaf(f1n, f1m[5], acc[i][5]) - sqv[5];
        o2.z = 2.f*fmaf(f1n, f1m[6], acc[i][6]) - sqv[6];
        o2.w = 2.f*fmaf(f1n, f1m[7], acc[i][7]) - sqv[7];
        *(float4*)&G[(size_t)row * NN + m0 + tx * 4]      = o1;
        *(float4*)&G[(size_t)row * NN + m0 + 64 + tx * 4] = o2;
    }
    if (a != bq) {
        // transposed write: rows m-range (128), cols n-range (64), minus sq[n]
#pragma unroll
        for (int j = 0; j < 8; ++j) {
            int cl = (j < 4) ? (tx * 4 + j) : (64 + tx * 4 + (j - 4));
            size_t grow = (size_t)(m0 + cl) * NN + n0 + ty * 4;
            float f1mj = f1m[j];
            float4 t0;
            t0.x = 2.f*fmaf(f1nv[0], f1mj, acc[0][j]) - sqn[0];
            t0.y = 2.f*fmaf(f1nv[1], f1mj, acc[1][j]) - sqn[1];
            t0.z = 2.f*fmaf(f1nv[2], f1mj, acc[2][j]) - sqn[2];
            t0.w = 2.f*fmaf(f1nv[3], f1mj, acc[3][j]) - sqn[3];
            *(float4*)&G[grow] = t0;
        }
    }
}

// ------- KSEL: per-row top-21 (drop first = self) -> idx[20], all batches ---
// float4 loads; slot i of lane l = column l*32+i. Exact top_k tie semantics.
__launch_bounds__(256)
__global__ void ksel(float* __restrict__ ws) {
    int wid = threadIdx.x >> 6, lane = threadIdx.x & 63;
    int r = blockIdx.x * 4 + wid;            // global row 0..16383 (= b*2048+n)
    const float* row = ws + G_OFF + (size_t)r * NN;
    float v[32];
#pragma unroll
    for (int i = 0; i < 8; ++i)
        *(float4*)&v[i * 4] = *(const float4*)&row[lane * 32 + i * 4];
    float b1v = -FLT_MAX, b2v = -FLT_MAX;
    int b1i = 0, b2i = 0;
#pragma unroll
    for (int i = 0; i < 32; ++i) {
        float x = v[i];
        if (x > b1v)      { b2v = b1v; b2i = b1i; b1v = x; b1i = i; }
        else if (x > b2v) { b2v = x; b2i = i; }
    }
    unsigned int mask = 0u;
    bool has2 = true;
    int* out = (int*)(ws + IDX_OFF) + (size_t)r * KNN;
    for (int k = 0; k < 21; ++k) {
        float M = b1v;
#pragma unroll
        for (int off = 1; off < 64; off <<= 1) M = fmaxf(M, __shfl_xor(M, off));
        unsigned long long tied = __ballot(b1v == M);
        int mm;
        if (__popcll(tied) > 1) {
            int cand = (b1v == M) ? ((lane << 5) | b1i) : 0x7FFFFFFF;
#pragma unroll
            for (int off = 1; off < 64; off <<= 1) {
                int oc = __shfl_xor(cand, off);
                cand = oc < cand ? oc : cand;
            }
            mm = cand;
        } else {
            int l = __ffsll(tied) - 1;
            mm = (l << 5) | __shfl(b1i, l);
        }
        if (k > 0 && lane == 0) out[k - 1] = mm;
        if (lane == (mm >> 5)) {
            mask |= 1u << b1i;
            if (has2) { b1v = b2v; b1i = b2i; has2 = false; }
            else {
                b1v = -FLT_MAX; b2v = -FLT_MAX; b1i = 0; b2i = 0;
#pragma unroll
                for (int i = 0; i < 32; ++i) {
                    float x = (mask & (1u << i)) ? -FLT_MAX : v[i];
                    if (x > b1v)      { b2v = b1v; b2i = b1i; b1v = x; b1i = i; }
                    else if (x > b2v) { b2v = x; b2i = i; }
                }
                has2 = true;
            }
        }
    }
}

// ---- K5: PQ[m][256] = F128[m][128] x Wcat128^T + f1[m]*wcol ---------------
__launch_bounds__(256)
__global__ void k5_pq(float* __restrict__ ws) {
    __shared__ __align__(16) float As[16][64];
    __shared__ __align__(16) float Bs[16][64];
    int tid = threadIdx.x;
    int m0 = blockIdx.x * 64, o0 = blockIdx.y * 64;
    int rr = tid >> 2, cq = tid & 3;
    int tx = tid & 15, ty = tid >> 4;
    float acc[4][4];
#pragma unroll
    for (int i = 0; i < 4; ++i)
#pragma unroll
        for (int j = 0; j < 4; ++j) acc[i][j] = 0.f;
    const float* F  = ws + F128_OFF;
    const float* Wc = ws + WCAT_OFF;
    for (int kc = 0; kc < 128; kc += 16) {
        float4 av = *(const float4*)&F [(size_t)(m0 + rr) * 128 + kc + cq * 4];
        float4 bv = *(const float4*)&Wc[(size_t)(o0 + rr) * 128 + kc + cq * 4];
        __syncthreads();
        As[cq*4+0][rr]=av.x; As[cq*4+1][rr]=av.y; As[cq*4+2][rr]=av.z; As[cq*4+3][rr]=av.w;
        Bs[cq*4+0][rr]=bv.x; Bs[cq*4+1][rr]=bv.y; Bs[cq*4+2][rr]=bv.z; Bs[cq*4+3][rr]=bv.w;
        __syncthreads();
#pragma unroll
        for (int kk = 0; kk < 16; ++kk) {
            float a[4], bb[4];
            *(float4*)&a[0]  = *(const float4*)&As[kk][ty * 4];
            *(float4*)&bb[0] = *(const float4*)&Bs[kk][tx * 4];
#pragma unroll
            for (int i = 0; i < 4; ++i)
#pragma unroll
                for (int j = 0; j < 4; ++j) acc[i][j] = fmaf(a[i], bb[j], acc[i][j]);
        }
    }
    float wc[4], f1v[4];
#pragma unroll
    for (int j = 0; j < 4; ++j) {
        wc[j]  = ws[WCOL_OFF + o0 + tx * 4 + j];
        f1v[j] = ws[F1_OFF + m0 + ty * 4 + j];
    }
#pragma unroll
    for (int i = 0; i < 4; ++i) {
        float4 o;
        o.x = fmaf(f1v[i], wc[0], acc[i][0]);
        o.y = fmaf(f1v[i], wc[1], acc[i][1]);
        o.z = fmaf(f1v[i], wc[2], acc[i][2]);
        o.w = fmaf(f1v[i], wc[3], acc[i][3]);
        *(float4*)&ws[PQ_OFF + (size_t)(m0 + ty * 4 + i) * 256 + o0 + tx * 4] = o;
    }
}

// -------- K6: bn0 stats + per-(m,o) min/max of (P - Q[j]) over neighbors ----
__launch_bounds__(256)
__global__ void k6_bn0stats(float* __restrict__ ws) {
    int tid = threadIdx.x;
    int o = tid & 127, h = tid >> 7;
    int m0 = blockIdx.x * 16;
    const float* PQ = ws + PQ_OFF;
    const int* idx = (const int*)(ws + IDX_OFF);
    float* MMn = ws + MMN_OFF;
    float* MMx = ws + MMX_OFF;
    __shared__ float red[2][128];
    float s = 0.f, q = 0.f;
    for (int p = h; p < 16; p += 2) {
        int m = m0 + p;
        int bb = m >> 11;
        float pv = PQ[(size_t)m * 256 + o];
        const int* ip = idx + (size_t)m * KNN;
        float mn = FLT_MAX, mx = -FLT_MAX;
        for (int k = 0; k < KNN; ++k) {
            int j = ip[k];
            float val = pv - PQ[(size_t)(bb * NN + j) * 256 + 128 + o];
            s += val; q += val * val;
            mn = fminf(mn, val); mx = fmaxf(mx, val);
        }
        MMn[(size_t)m * NC + o] = mn;
        MMx[(size_t)m * NC + o] = mx;
    }
    red[h][o] = s; __syncthreads();
    if (tid < 128) atomicAdd(&ws[BN0S_OFF + tid], red[0][tid] + red[1][tid]);
    __syncthreads();
    red[h][o] = q; __syncthreads();
    if (tid < 128) atomicAdd(&ws[BN0S_OFF + 128 + tid], red[0][tid] + red[1][tid]);
}

// ---- K8: X0 = relu(sc * (sc>0 ? max : min) + sh); affine derived inline ----
__launch_bounds__(256)
__global__ void k8_apply(float* __restrict__ ws, const float* __restrict__ g,
                         const float* __restrict__ be) {
    int e = blockIdx.x * 256 + threadIdx.x;
    int fi = e * 4;
    int o = fi & 127;
    const float cnt = 1.f / (float)(NB * NN * KNN);
    float4 sum4 = *(const float4*)&ws[BN0S_OFF + o];
    float4 ssq4 = *(const float4*)&ws[BN0S_OFF + 128 + o];
    float4 g4   = *(const float4*)&g[o];
    float4 be4  = *(const float4*)&be[o];
    float4 mn = *(const float4*)&ws[MMN_OFF + fi];
    float4 mx = *(const float4*)&ws[MMX_OFF + fi];
    float4 r;
#define BN0_DO(comp) { \
    float m_ = sum4.comp * cnt; \
    float v_ = ssq4.comp * cnt - m_ * m_; if (v_ < 0.f) v_ = 0.f; \
    float sc_ = g4.comp * rsqrtf(v_ + EPSV); \
    float sh_ = be4.comp - m_ * sc_; \
    r.comp = fmaxf(fmaf(sc_ > 0.f ? mx.comp : mn.comp, sc_, sh_), 0.f); }
    BN0_DO(x) BN0_DO(y) BN0_DO(z) BN0_DO(w)
#undef BN0_DO
    *(float4*)&ws[X_OFF + fi] = r;
}

// ---- K9f: res conv GEMM (64m x 64o tiles) + fused per-(b,o) stats.
// If statsIn: derive per-(block-batch) inorm+bn affine from raw stats;
// input t = relu(x*sc + sh [+ xin]). If xw && blockIdx.y==0: write t back.
__launch_bounds__(256)
__global__ void k9f_conv(const float* __restrict__ x, const float* __restrict__ w,
                         float* __restrict__ y, float* __restrict__ stats,
                         const float* __restrict__ statsIn,
                         const float* __restrict__ g, const float* __restrict__ be,
                         const float* __restrict__ xin, float* __restrict__ xw) {
    __shared__ __align__(16) float As[16][64];
    __shared__ __align__(16) float Bs[16][64];
    __shared__ float red[16][64];
    __shared__ float vvv[8][128];
    __shared__ float scs[128], shs[128];
    int tid = threadIdx.x;
    int m0 = blockIdx.x * 64, o0 = blockIdx.y * 64;
    int bA = m0 >> 11;                       // whole block is one batch (64 | 2048)
    if (statsIn) {
        for (int e = tid; e < 1024; e += 256) {
            float sum = statsIn[e], ssq = statsIn[1024 + e];
            float m_ = sum * (1.f / (float)NN);
            float v_ = ssq * (1.f / (float)NN) - m_ * m_; if (v_ < 0.f) v_ = 0.f;
            vvv[e >> 7][e & 127] = v_ / (v_ + EPSV);
        }
        __syncthreads();
        if (tid < 128) {
            float a = 0.f;
#pragma unroll
            for (int b2 = 0; b2 < NB; ++b2) a += vvv[b2][tid];
            float rsbn = rsqrtf(a * (1.f / (float)NB) + EPSV);
            float sum = statsIn[bA * 128 + tid], ssq = statsIn[1024 + bA * 128 + tid];
            float m_ = sum * (1.f / (float)NN);
            float v_ = ssq * (1.f / (float)NN) - m_ * m_; if (v_ < 0.f) v_ = 0.f;
            float sc_ = rsqrtf(v_ + EPSV) * rsbn * g[tid];
            scs[tid] = sc_;
            shs[tid] = be[tid] - m_ * sc_;
        }
        __syncthreads();
    }
    int rr = tid >> 2, cq = tid & 3;
    int tx = tid & 15, ty = tid >> 4;
    float acc[4][4];
#pragma unroll
    for (int i = 0; i < 4; ++i)
#pragma unroll
        for (int j = 0; j < 4; ++j) acc[i][j] = 0.f;
    for (int kc = 0; kc < NC; kc += 16) {
        float4 av = *(const float4*)&x[(size_t)(m0 + rr) * NC + kc + cq * 4];
        if (statsIn) {
            int c = kc + cq * 4;
            av.x = fmaf(av.x, scs[c],     shs[c]);
            av.y = fmaf(av.y, scs[c + 1], shs[c + 1]);
            av.z = fmaf(av.z, scs[c + 2], shs[c + 2]);
            av.w = fmaf(av.w, scs[c + 3], shs[c + 3]);
            if (xin) {
                float4 xv = *(const float4*)&xin[(size_t)(m0 + rr) * NC + kc + cq * 4];
                av.x += xv.x; av.y += xv.y; av.z += xv.z; av.w += xv.w;
            }
            av.x = fmaxf(av.x, 0.f); av.y = fmaxf(av.y, 0.f);
            av.z = fmaxf(av.z, 0.f); av.w = fmaxf(av.w, 0.f);
            if (xw && blockIdx.y == 0)
                *(float4*)&xw[(size_t)(m0 + rr) * NC + kc + cq * 4] = av;
        }
        float4 bv = *(const float4*)&w[(size_t)(o0 + rr) * NC + kc + cq * 4];
        __syncthreads();
        As[cq*4+0][rr]=av.x; As[cq*4+1][rr]=av.y; As[cq*4+2][rr]=av.z; As[cq*4+3][rr]=av.w;
        Bs[cq*4+0][rr]=bv.x; Bs[cq*4+1][rr]=bv.y; Bs[cq*4+2][rr]=bv.z; Bs[cq*4+3][rr]=bv.w;
        __syncthreads();
#pragma unroll
        for (int kk = 0; kk < 16; ++kk) {
            float a[4], bb[4];
            *(float4*)&a[0]  = *(const float4*)&As[kk][ty * 4];
            *(float4*)&bb[0] = *(const float4*)&Bs[kk][tx * 4];
#pragma unroll
            for (int i = 0; i < 4; ++i)
#pragma unroll
                for (int j = 0; j < 4; ++j) acc[i][j] = fmaf(a[i], bb[j], acc[i][j]);
        }
    }
#pragma unroll
    for (int i = 0; i < 4; ++i) {
        float4 o;
        o.x = acc[i][0]; o.y = acc[i][1]; o.z = acc[i][2]; o.w = acc[i][3];
        *(float4*)&y[(size_t)(m0 + ty * 4 + i) * NC + o0 + tx * 4] = o;
    }
    float s[4], q[4];
#pragma unroll
    for (int j = 0; j < 4; ++j) {
        s[j] = acc[0][j] + acc[1][j] + acc[2][j] + acc[3][j];
        q[j] = acc[0][j]*acc[0][j] + acc[1][j]*acc[1][j] + acc[2][j]*acc[2][j] + acc[3][j]*acc[3][j];
    }
    *(float4*)&red[ty][tx * 4] = make_float4(s[0], s[1], s[2], s[3]);
    __syncthreads();
    if (tid < 64) {
        float t = 0.f;
#pragma unroll
        for (int g2 = 0; g2 < 16; ++g2) t += red[g2][tid];
        atomicAdd(&stats[bA * NC + o0 + tid], t);
    }
    __syncthreads();
    *(float4*)&red[ty][tx * 4] = make_float4(q[0], q[1], q[2], q[3]);
    __syncthreads();
    if (tid < 64) {
        float t = 0.f;
#pragma unroll
        for (int g2 = 0; g2 < 16; ++g2) t += red[g2][tid];
        atomicAdd(&stats[1024 + bA * NC + o0 + tid], t);
    }
}

// ---- K12: logit = lin_w . relu(aff7(y2) + xin) + lin_b; aff derived inline -
__launch_bounds__(256)
__global__ void k12_logit(const float* __restrict__ y2, const float* __restrict__ xin,
                          const float* __restrict__ statsIn,
                          const float* __restrict__ g, const float* __restrict__ be,
                          const float* __restrict__ lw, const float* __restrict__ lb,
                          float* __restrict__ out) {
    __shared__ float wsh[128];
    __shared__ float vvv[8][128];
    __shared__ float scs[128], shs[128];
    int tid = threadIdx.x;
    int b = (blockIdx.x * 256) >> 11;        // whole block one batch (256 | 2048)
    if (tid < 128) wsh[tid] = lw[tid];
    for (int e = tid; e < 1024; e += 256) {
        float sum = statsIn[e], ssq = statsIn[1024 + e];
        float m_ = sum * (1.f / (float)NN);
        float v_ = ssq * (1.f / (float)NN) - m_ * m_; if (v_ < 0.f) v_ = 0.f;
        vvv[e >> 7][e & 127] = v_ / (v_ + EPSV);
    }
    __syncthreads();
    if (tid < 128) {
        float a = 0.f;
#pragma unroll
        for (int b2 = 0; b2 < NB; ++b2) a += vvv[b2][tid];
        float rsbn = rsqrtf(a * (1.f / (float)NB) + EPSV);
        float sum = statsIn[b * 128 + tid], ssq = statsIn[1024 + b * 128 + tid];
        float m_ = sum * (1.f / (float)NN);
        float v_ = ssq * (1.f / (float)NN) - m_ * m_; if (v_ < 0.f) v_ = 0.f;
        float sc_ = rsqrtf(v_ + EPSV) * rsbn * g[tid];
        scs[tid] = sc_;
        shs[tid] = be[tid] - m_ * sc_;
    }
    __syncthreads();
    int m = blockIdx.x * 256 + tid;
    const float* yp = y2 + (size_t)m * NC;
    const float* xp = xin + (size_t)m * NC;
    float acc = lb[0];
    for (int c = 0; c < NC; c += 4) {
        float4 yv = *(const float4*)&yp[c];
        float4 xv = *(const float4*)&xp[c];
        float v0 = fmaxf(fmaf(yv.x, scs[c],     shs[c])     + xv.x, 0.f);
        float v1 = fmaxf(fmaf(yv.y, scs[c + 1], shs[c + 1]) + xv.y, 0.f);
        float v2 = fmaxf(fmaf(yv.z, scs[c + 2], shs[c + 2]) + xv.z, 0.f);
        float v3 = fmaxf(fmaf(yv.w, scs[c + 3], shs[c + 3]) + xv.w, 0.f);
        acc += v0 * wsh[c] + v1 * wsh[c + 1] + v2 * wsh[c + 2] + v3 * wsh[c + 3];
    }
    out[m] = acc;
}

extern "C" void kernel_launch(void* const* d_in, const int* in_sizes, int n_in,
                              void* d_out, int out_size, void* d_ws, size_t ws_size,
                              hipStream_t stream) {
    if (ws_size < (size_t)WS_FLOATS * 4) return;  // fail visibly (zero output)
    const float* data    = (const float*)d_in[0];
    const float* conv0_w = (const float*)d_in[2];
    const float* bn0_g   = (const float*)d_in[4];
    const float* bn0_b   = (const float*)d_in[5];
    const float* lin_w   = (const float*)d_in[6];
    const float* lin_b   = (const float*)d_in[7];
    const float* res_w1  = (const float*)d_in[8];
    const float* res_g1  = (const float*)d_in[10];
    const float* res_be1 = (const float*)d_in[11];
    const float* res_w2  = (const float*)d_in[12];
    const float* res_g2  = (const float*)d_in[14];
    const float* res_be2 = (const float*)d_in[15];
    float* ws  = (float*)d_ws;
    float* out = (float*)d_out;

    hipMemsetAsync(d_ws, 0, ZERO_CNT * sizeof(float), stream);
    k1_fused<<<dim3(32, 8), 256, 0, stream>>>(data, ws);
    k2_feat<<<dim3(32, 8), 256, 0, stream>>>(data, ws);
    k4_wcat<<<130, 256, 0, stream>>>(conv0_w, ws);
    k3_gram<<<dim3(272, 1, 8), 256, 0, stream>>>(ws);
    ksel<<<4096, 256, 0, stream>>>(ws);
    k5_pq<<<dim3(256, 4), 256, 0, stream>>>(ws);
    k6_bn0stats<<<1024, 256, 0, stream>>>(ws);
    k8_apply<<<2048, 256, 0, stream>>>(ws, bn0_g, bn0_b);

    float* XA = ws + X_OFF;
    float* Y1 = ws + X_OFF + SLOT_SZ;
    float* Y2 = ws + X_OFF + 2 * SLOT_SZ;
    float* XB = ws + XB_OFF;
    float* ST = ws + RESST_OFF;

    // Layer 0 (x0 = XA, materialized by k8)
    k9f_conv<<<dim3(256, 2), 256, 0, stream>>>(XA, res_w1, Y1, ST,
                                               nullptr, nullptr, nullptr, nullptr, nullptr);
    k9f_conv<<<dim3(256, 2), 256, 0, stream>>>(Y1, res_w2, Y2, ST + 2048,
                                               ST, res_g1, res_be1, nullptr, nullptr);
    // Layers 1..3: conv1 consumes (Y2 w/ aff(2i-1), + x_prev), materializes x_i
    float* xcur = XA; float* xnext = XB;
    for (int i = 1; i < 4; ++i) {
        int L = 2 * i, L2 = 2 * i + 1;
        k9f_conv<<<dim3(256, 2), 256, 0, stream>>>(Y2, res_w1 + i * 16384, Y1, ST + L * 2048,
                                                   ST + (L - 1) * 2048,
                                                   res_g2 + (i - 1) * 128, res_be2 + (i - 1) * 128,
                                                   xcur, xnext);
        k9f_conv<<<dim3(256, 2), 256, 0, stream>>>(Y1, res_w2 + i * 16384, Y2, ST + L2 * 2048,
                                                   ST + L * 2048,
                                                   res_g1 + i * 128, res_be1 + i * 128,
                                                   nullptr, nullptr);
        float* t = xcur; xcur = xnext; xnext = t;
    }
    // Final: logit on x4 = relu(aff7(Y2) + x3), x3 is in xcur
    k12_logit<<<64, 256, 0, stream>>>(Y2, xcur, ST + 7 * 2048, res_g2 + 3 * 128, res_be2 + 3 * 128,
                                      lin_w, lin_b, out);
}